// Round 6
// baseline (142.849 us; speedup 1.0000x reference)
//
#include <hip/hip_runtime.h>

// CalculateSLayer: A = adj[:,:,0]+adj[:,:,1]  (L x L, L=4096)
//   h_in  = A^T @ h   (output 0)
//   h_out = A   @ h   (output 1)
// Round 6: keep round-5's streaming convert (adj -> fp16 fragment-order AF /
// ATF, ~6.3 TB/s) and reduce kernel; rebuild the gemm. B-fragments are now
// precomputed contiguous (BF, 1.31 MB, L2-resident) killing round-5's
// 16-segment B-load scatter; each wave register-blocks M=2 row-tiles x 10
// d-tiles over K=512 (12 loads : 20 MFMA per step); wave pairs in a block
// cover adjacent K-halves and combine in LDS so partial count stays at 8.

typedef _Float16 half8 __attribute__((ext_vector_type(8)));
typedef float f32x4 __attribute__((ext_vector_type(4)));

#define LL 4096
#define DD 150
#define RPAD 162
#define LLDD (LL * DD)                    // 614400
#define BF_BYTES ((size_t)10 * 128 * 512 * 2)   // 1310720
#define P_BYTES ((size_t)8 * LLDD * 4)          // 19660800
#define TS 72                             // convert LDS tile row stride (halfs)

// BF unit (nt, S): 64 lanes x 8 halfs; lane (r=l&15, g=l>>4), elem e holds
// B[k = S*32+g*8+e][n = nt*16+r] = h[S*32+g*8+e][nt*16+r]  (B-operand layout,
// identical element mapping to the round-5-verified HT indexing).
__global__ __launch_bounds__(256) void prep_kernel(const float* __restrict__ h,
                                                   _Float16* __restrict__ BF) {
    const int lg = blockIdx.x * 256 + threadIdx.x;   // 10*128*64 = 81920 lane-units
    const int u = lg >> 6, l = lg & 63;
    const int nt = u >> 7, S = u & 127;
    const int r = l & 15, g = l >> 4;
    const int d = nt * 16 + r;
    const int j0 = S * 32 + g * 8;
    half8 v;
#pragma unroll
    for (int e = 0; e < 8; ++e)
        v[e] = (d < DD) ? (_Float16)h[(size_t)(j0 + e) * DD + d] : (_Float16)0.0f;
    *(half8*)(BF + (size_t)lg * 8) = v;
}

// Streams one 64x64 tile of A: coalesced adj read, fp16-sum, emits A-operand
// fragment units (verified rounds 1-5). AF: rows of A over k=j; ATF: rows of
// A^T over k=i. Unit (T,S) elem: A[T*16+r][S*32+g*8+e].
__global__ __launch_bounds__(256) void convert_kernel(const float* __restrict__ adj,
                                                      _Float16* __restrict__ AF,
                                                      _Float16* __restrict__ ATF) {
    __shared__ _Float16 T64[64][TS];   // 9216 B
    const int tid = threadIdx.x;
    const int bi = blockIdx.x >> 6;    // i-block 0..63
    const int bj = blockIdx.x & 63;    // j-block 0..63
    const float4* adj4 = (const float4*)adj;

#pragma unroll
    for (int it = 0; it < 8; ++it) {
        const int vidx = it * 256 + tid;
        const int il = vidx >> 5, jq = vidx & 31;
        const float4 v = adj4[(size_t)(bi * 64 + il) * 2048 + bj * 32 + jq];
        union { _Float16 h[2]; unsigned u; } p;
        p.h[0] = (_Float16)(v.x + v.y);
        p.h[1] = (_Float16)(v.z + v.w);
        *(unsigned*)((char*)&T64[il][0] + jq * 4) = p.u;
    }
    __syncthreads();

    const int wave = tid >> 6, lane = tid & 63;
    const int r = lane & 15, g = lane >> 4;
#pragma unroll
    for (int c = 0; c < 2; ++c) {
        const half8 va = *(const half8*)((const char*)&T64[wave * 16 + r][0]
                                         + (c * 32 + g * 8) * 2);
        *(half8*)(AF + ((size_t)(bi * 4 + wave) * 128 + (bj * 2 + c)) * 512
                  + lane * 8) = va;
        half8 vt;
#pragma unroll
        for (int e = 0; e < 8; ++e) vt[e] = T64[c * 32 + g * 8 + e][wave * 16 + r];
        *(half8*)(ATF + ((size_t)(bj * 4 + wave) * 128 + (bi * 2 + c)) * 512
                  + lane * 8) = vt;
    }
}

// Barrier-light GEMM. Block b: output = (b<256 ? h_out : h_in); bb = b&255;
// bRow = bb&63 (64-row group), ks = bb>>6 (K-slice of 1024 for the P fan-in).
// Wave w: rp = w>>1 (which 32-row half), ksub = w&1 (which 512-K half).
// Per k-step: 2 A-frag + 10 B-frag contiguous loads, 20 MFMAs. Epilogue:
// ksub halves combine via LDS atomics, then one coalesced P write.
__global__ __launch_bounds__(256, 2) void gemm_kernel(const _Float16* __restrict__ AF,
                                                      const _Float16* __restrict__ ATF,
                                                      const _Float16* __restrict__ BF,
                                                      float* __restrict__ P) {
    __shared__ float red[64][RPAD];   // 41.5 KB
    const int tid = threadIdx.x;
    const int wave = tid >> 6, lane = tid & 63;
    const int r = lane & 15, g = lane >> 4;
    const int b = blockIdx.x;
    const int isIn = b >> 8;           // 0: h_out (AF), 1: h_in (ATF)
    const int bb = b & 255;
    const int bRow = bb & 63, ks = bb >> 6;
    const int rp = wave >> 1, ksub = wave & 1;
    const int T0 = bRow * 4 + rp * 2;
    const int S0 = ks * 32 + ksub * 16;     // global 32-K step base

    for (int e = tid; e < 64 * RPAD; e += 256) (&red[0][0])[e] = 0.f;

    const _Float16* base = isIn ? ATF : AF;
    const _Float16* f0 = base + ((size_t)T0 * 128 + S0) * 512 + lane * 8;
    const _Float16* f1 = f0 + (size_t)128 * 512;
    const _Float16* bf = BF + (size_t)S0 * 512 + lane * 8;

    f32x4 acc0[10], acc1[10];
#pragma unroll
    for (int nt = 0; nt < 10; ++nt) {
        acc0[nt] = (f32x4){0.f, 0.f, 0.f, 0.f};
        acc1[nt] = (f32x4){0.f, 0.f, 0.f, 0.f};
    }
#pragma unroll 2
    for (int s = 0; s < 16; ++s) {
        const half8 a0 = *(const half8*)(f0 + (size_t)s * 512);
        const half8 a1 = *(const half8*)(f1 + (size_t)s * 512);
#pragma unroll
        for (int nt = 0; nt < 10; ++nt) {
            const half8 bv = *(const half8*)(bf + ((size_t)nt * 128 + s) * 512);
            acc0[nt] = __builtin_amdgcn_mfma_f32_16x16x32_f16(a0, bv, acc0[nt], 0, 0, 0);
            acc1[nt] = __builtin_amdgcn_mfma_f32_16x16x32_f16(a1, bv, acc1[nt], 0, 0, 0);
        }
    }
    __syncthreads();   // red zeroed by all
    // D layout: row = g*4+u, col = r (verified rounds 1-5)
#pragma unroll
    for (int nt = 0; nt < 10; ++nt)
#pragma unroll
        for (int u = 0; u < 4; ++u) {
            atomicAdd(&red[rp * 32 + g * 4 + u][nt * 16 + r], acc0[nt][u]);
            atomicAdd(&red[rp * 32 + 16 + g * 4 + u][nt * 16 + r], acc1[nt][u]);
        }
    __syncthreads();
    float* dst = P + (size_t)(isIn * 4 + ks) * LLDD + (size_t)bRow * 64 * DD;
    for (int e = tid; e < 64 * DD; e += 256)
        dst[e] = red[e / DD][e % DD];
}

// out[0:LLDD) = h_in = sum P[4..7]; out[LLDD:2*LLDD) = h_out = sum P[0..3]
__global__ __launch_bounds__(256) void reduce_kernel(const float* __restrict__ P,
                                                     float* __restrict__ out) {
    const int idx = blockIdx.x * 256 + threadIdx.x;
    const int nv = LLDD / 4;
    const float4* p = (const float4*)P;
    const float4* src = (idx < nv) ? (p + (size_t)4 * nv) : p;
    const int e = (idx < nv) ? idx : idx - nv;
    const float4 a = src[e], b = src[e + nv], c = src[e + 2 * nv], d = src[e + 3 * nv];
    float4 s;
    s.x = (a.x + b.x) + (c.x + d.x);
    s.y = (a.y + b.y) + (c.y + d.y);
    s.z = (a.z + b.z) + (c.z + d.z);
    s.w = (a.w + b.w) + (c.w + d.w);
    ((float4*)out)[idx] = s;
}

extern "C" void kernel_launch(void* const* d_in, const int* in_sizes, int n_in,
                              void* d_out, int out_size, void* d_ws, size_t ws_size,
                              hipStream_t stream) {
    const float* adj = (const float*)d_in[0];   // [4096, 4096, 2] fp32
    const float* h   = (const float*)d_in[1];   // [4096, 150] fp32
    float* out = (float*)d_out;
    _Float16* BF = (_Float16*)d_ws;                               // 1.31 MB
    float* P = (float*)((char*)d_ws + BF_BYTES);                  // 19.66 MB
    _Float16* AF = (_Float16*)((char*)d_ws + BF_BYTES + P_BYTES); // 33.55 MB
    _Float16* ATF = AF + (size_t)16777216;                        // 33.55 MB

    hipLaunchKernelGGL(prep_kernel, dim3(320), dim3(256), 0, stream, h, BF);
    hipLaunchKernelGGL(convert_kernel, dim3(4096), dim3(256), 0, stream, adj, AF, ATF);
    hipLaunchKernelGGL(gemm_kernel, dim3(512), dim3(256), 0, stream, AF, ATF, BF, P);
    hipLaunchKernelGGL(reduce_kernel, dim3(2 * LLDD / 4 / 256), dim3(256), 0, stream,
                       P, out);
}

// Round 7
// 67.969 us; speedup vs baseline: 2.1017x; 2.1017x over previous
//
#include <hip/hip_runtime.h>

// CalculateSLayer: A = adj[:,:,0]+adj[:,:,1]  (L x L, L=4096)
//   h_in  = A^T @ h   (output 0)
//   h_out = A   @ h   (output 1)
// Round 7: gemm rebuilt on the m97-proven pattern: async global_load_lds
// staging of fragment-ordered fp16 (AF/ATF/BF all linear by construction),
// double-buffered 2-phase loop (stage next -> ds_read+MFMA cur -> barrier).
// prep/convert/reduce kernels unchanged (proven). No atomics.

typedef _Float16 half8 __attribute__((ext_vector_type(8)));
typedef float f32x4 __attribute__((ext_vector_type(4)));

#define LL 4096
#define DD 150
#define LLDD (LL * DD)                    // 614400
#define BF_BYTES ((size_t)10 * 128 * 512 * 2)   // 1310720
#define P_BYTES ((size_t)8 * LLDD * 4)          // 19660800
#define TS 72                             // convert LDS tile row stride (halfs)

// BF unit (nt, S): 64 lanes x 8 halfs; lane (r=l&15, g=l>>4), elem e holds
// B[k = S*32+g*8+e][n = nt*16+r] = h[k][nt*16+r]  (verified rounds 5-6).
__global__ __launch_bounds__(256) void prep_kernel(const float* __restrict__ h,
                                                   _Float16* __restrict__ BF) {
    const int lg = blockIdx.x * 256 + threadIdx.x;   // 81920 lane-units
    const int u = lg >> 6, l = lg & 63;
    const int nt = u >> 7, S = u & 127;
    const int r = l & 15, g = l >> 4;
    const int d = nt * 16 + r;
    const int j0 = S * 32 + g * 8;
    half8 v;
#pragma unroll
    for (int e = 0; e < 8; ++e)
        v[e] = (d < DD) ? (_Float16)h[(size_t)(j0 + e) * DD + d] : (_Float16)0.0f;
    *(half8*)(BF + (size_t)lg * 8) = v;
}

// Streams one 64x64 tile of A: coalesced adj read, fp16-sum, emits A-operand
// fragment units (verified rounds 1-6). Unit (T,S) elem: A[T*16+r][S*32+g*8+e].
__global__ __launch_bounds__(256) void convert_kernel(const float* __restrict__ adj,
                                                      _Float16* __restrict__ AF,
                                                      _Float16* __restrict__ ATF) {
    __shared__ _Float16 T64[64][TS];   // 9216 B
    const int tid = threadIdx.x;
    const int bi = blockIdx.x >> 6;
    const int bj = blockIdx.x & 63;
    const float4* adj4 = (const float4*)adj;

#pragma unroll
    for (int it = 0; it < 8; ++it) {
        const int vidx = it * 256 + tid;
        const int il = vidx >> 5, jq = vidx & 31;
        const float4 v = adj4[(size_t)(bi * 64 + il) * 2048 + bj * 32 + jq];
        union { _Float16 h[2]; unsigned u; } p;
        p.h[0] = (_Float16)(v.x + v.y);
        p.h[1] = (_Float16)(v.z + v.w);
        *(unsigned*)((char*)&T64[il][0] + jq * 4) = p.u;
    }
    __syncthreads();

    const int wave = tid >> 6, lane = tid & 63;
    const int r = lane & 15, g = lane >> 4;
#pragma unroll
    for (int c = 0; c < 2; ++c) {
        const half8 va = *(const half8*)((const char*)&T64[wave * 16 + r][0]
                                         + (c * 32 + g * 8) * 2);
        *(half8*)(AF + ((size_t)(bi * 4 + wave) * 128 + (bj * 2 + c)) * 512
                  + lane * 8) = va;
        half8 vt;
#pragma unroll
        for (int e = 0; e < 8; ++e) vt[e] = T64[c * 32 + g * 8 + e][wave * 16 + r];
        *(half8*)(ATF + ((size_t)(bj * 4 + wave) * 128 + (bi * 2 + c)) * 512
                  + lane * 8) = vt;
    }
}

// gemm v2 (m97 pattern). Block: 4 waves; owns output half (h_out/h_in),
// 4 M-tiles (T0..T0+3, wave w -> T0+w), 5 n-tiles (nh half), K-slice 1024
// (32 S-steps, 8 chunks of 4). Chunk = 36 LDS units of 1 KB: u<16 A(T=u>>2,
// s=u&3), u>=16 B(nt=(u-16)>>2, s=(u-16)&3). Stage via global_load_lds
// width 16 (linear frag layout = gload-compatible by construction).
__global__ __launch_bounds__(256, 2) void gemm_kernel(const _Float16* __restrict__ AF,
                                                      const _Float16* __restrict__ ATF,
                                                      const _Float16* __restrict__ BF,
                                                      float* __restrict__ P) {
    __shared__ __align__(16) _Float16 lds[2][36 * 512];   // 73728 B
    const int tid = threadIdx.x;
    const int wave = tid >> 6, lane = tid & 63;
    const int r = lane & 15, g = lane >> 4;

    // bijective XCD swizzle (nwg=1024, %8==0): contiguous 128-chunk per XCD
    const int o = (blockIdx.x & 7) * 128 + (blockIdx.x >> 3);
    const int ks = o & 3;              // K-split slice
    const int nh = (o >> 2) & 1;       // n-half: nt 0..4 or 5..9
    const int Mblk = (o >> 3) & 63;
    const int isIn = (o >> 9) & 1;     // 0: h_out (AF), 1: h_in (ATF)

    const _Float16* Asrc = isIn ? ATF : AF;
    const int T0 = Mblk * 4;
    const int Sbase = ks * 32;

    f32x4 acc[5];
#pragma unroll
    for (int q = 0; q < 5; ++q) acc[q] = (f32x4){0.f, 0.f, 0.f, 0.f};

    // ---- stage chunk 0 ----
    {
        const int chunkS = Sbase;
#pragma unroll
        for (int k = 0; k < 9; ++k) {
            const int u = wave * 9 + k;
            const _Float16* src;
            if (u < 16) {
                src = Asrc + ((size_t)(T0 + (u >> 2)) * 128 + chunkS + (u & 3)) * 512;
            } else {
                const int v = u - 16;
                src = BF + ((size_t)(nh * 5 + (v >> 2)) * 128 + chunkS + (v & 3)) * 512;
            }
            __builtin_amdgcn_global_load_lds(
                (const __attribute__((address_space(1))) void*)(src + lane * 8),
                (__attribute__((address_space(3))) void*)(&lds[0][u * 512]),
                16, 0, 0);
        }
    }
    __syncthreads();

    for (int c = 0; c < 8; ++c) {
        const int buf = c & 1;
        if (c < 7) {   // issue next-chunk stage BEFORE compute (T3-minimal)
            const int chunkS = Sbase + (c + 1) * 4;
#pragma unroll
            for (int k = 0; k < 9; ++k) {
                const int u = wave * 9 + k;
                const _Float16* src;
                if (u < 16) {
                    src = Asrc + ((size_t)(T0 + (u >> 2)) * 128 + chunkS + (u & 3)) * 512;
                } else {
                    const int v = u - 16;
                    src = BF + ((size_t)(nh * 5 + (v >> 2)) * 128 + chunkS + (v & 3)) * 512;
                }
                __builtin_amdgcn_global_load_lds(
                    (const __attribute__((address_space(1))) void*)(src + lane * 8),
                    (__attribute__((address_space(3))) void*)(&lds[buf ^ 1][u * 512]),
                    16, 0, 0);
            }
        }
        // ---- compute chunk c from lds[buf] ----
        half8 a[4];
#pragma unroll
        for (int s = 0; s < 4; ++s)
            a[s] = *(const half8*)(&lds[buf][(wave * 4 + s) * 512 + lane * 8]);
#pragma unroll
        for (int q = 0; q < 5; ++q)
#pragma unroll
            for (int s = 0; s < 4; ++s) {
                const half8 b = *(const half8*)(&lds[buf][(16 + q * 4 + s) * 512
                                                          + lane * 8]);
                acc[q] = __builtin_amdgcn_mfma_f32_16x16x32_f16(a[s], b, acc[q], 0, 0, 0);
            }
        __syncthreads();   // drains this wave's gload_lds; releases buf for overwrite
    }

    // D layout: row = g*4+u, col = r (verified rounds 1-6)
    float* dst = P + (size_t)(isIn * 4 + ks) * LLDD;
    const int row = (T0 + wave) * 16 + g * 4;
#pragma unroll
    for (int q = 0; q < 5; ++q) {
        const int d = (nh * 5 + q) * 16 + r;
        if (d < DD) {
#pragma unroll
            for (int u = 0; u < 4; ++u)
                dst[(size_t)(row + u) * DD + d] = acc[q][u];
        }
    }
}

// out[0:LLDD) = h_in = sum P[4..7]; out[LLDD:2*LLDD) = h_out = sum P[0..3]
__global__ __launch_bounds__(256) void reduce_kernel(const float* __restrict__ P,
                                                     float* __restrict__ out) {
    const int idx = blockIdx.x * 256 + threadIdx.x;
    const int nv = LLDD / 4;
    const float4* p = (const float4*)P;
    const float4* src = (idx < nv) ? (p + (size_t)4 * nv) : p;
    const int e = (idx < nv) ? idx : idx - nv;
    const float4 a = src[e], b = src[e + nv], c = src[e + 2 * nv], d = src[e + 3 * nv];
    float4 s;
    s.x = (a.x + b.x) + (c.x + d.x);
    s.y = (a.y + b.y) + (c.y + d.y);
    s.z = (a.z + b.z) + (c.z + d.z);
    s.w = (a.w + b.w) + (c.w + d.w);
    ((float4*)out)[idx] = s;
}

extern "C" void kernel_launch(void* const* d_in, const int* in_sizes, int n_in,
                              void* d_out, int out_size, void* d_ws, size_t ws_size,
                              hipStream_t stream) {
    const float* adj = (const float*)d_in[0];   // [4096, 4096, 2] fp32
    const float* h   = (const float*)d_in[1];   // [4096, 150] fp32
    float* out = (float*)d_out;
    _Float16* BF = (_Float16*)d_ws;                               // 1.31 MB
    float* P = (float*)((char*)d_ws + BF_BYTES);                  // 19.66 MB
    _Float16* AF = (_Float16*)((char*)d_ws + BF_BYTES + P_BYTES); // 33.55 MB
    _Float16* ATF = AF + (size_t)16777216;                        // 33.55 MB

    hipLaunchKernelGGL(prep_kernel, dim3(320), dim3(256), 0, stream, h, BF);
    hipLaunchKernelGGL(convert_kernel, dim3(4096), dim3(256), 0, stream, adj, AF, ATF);
    hipLaunchKernelGGL(gemm_kernel, dim3(1024), dim3(256), 0, stream, AF, ATF, BF, P);
    hipLaunchKernelGGL(reduce_kernel, dim3(2 * LLDD / 4 / 256), dim3(256), 0, stream,
                       P, out);
}

// Round 8
// 61.437 us; speedup vs baseline: 2.3251x; 1.1063x over previous
//
#include <hip/hip_runtime.h>

// CalculateSLayer: A = adj[:,:,0]+adj[:,:,1]  (L x L, L=4096)
//   h_in  = A^T @ h   (output 0)
//   h_out = A   @ h   (output 1)
// Round 8: round-7's proven gload_lds gemm with K-split 4 -> 2 (halves the
// partial/reduce round-trip traffic). prep/convert unchanged. No atomics.

typedef _Float16 half8 __attribute__((ext_vector_type(8)));
typedef float f32x4 __attribute__((ext_vector_type(4)));

#define LL 4096
#define DD 150
#define LLDD (LL * DD)                    // 614400
#define BF_BYTES ((size_t)10 * 128 * 512 * 2)   // 1310720
#define P_BYTES ((size_t)4 * LLDD * 4)          // 9830400 (4 slices now)
#define TS 72                             // convert LDS tile row stride (halfs)

// BF unit (nt, S): 64 lanes x 8 halfs; lane (r=l&15, g=l>>4), elem e holds
// B[k = S*32+g*8+e][n = nt*16+r] = h[k][nt*16+r]  (verified rounds 5-7).
__global__ __launch_bounds__(256) void prep_kernel(const float* __restrict__ h,
                                                   _Float16* __restrict__ BF) {
    const int lg = blockIdx.x * 256 + threadIdx.x;   // 81920 lane-units
    const int u = lg >> 6, l = lg & 63;
    const int nt = u >> 7, S = u & 127;
    const int r = l & 15, g = l >> 4;
    const int d = nt * 16 + r;
    const int j0 = S * 32 + g * 8;
    half8 v;
#pragma unroll
    for (int e = 0; e < 8; ++e)
        v[e] = (d < DD) ? (_Float16)h[(size_t)(j0 + e) * DD + d] : (_Float16)0.0f;
    *(half8*)(BF + (size_t)lg * 8) = v;
}

// Streams one 64x64 tile of A: coalesced adj read, fp16-sum, emits A-operand
// fragment units (verified rounds 1-7). Unit (T,S) elem: A[T*16+r][S*32+g*8+e].
__global__ __launch_bounds__(256) void convert_kernel(const float* __restrict__ adj,
                                                      _Float16* __restrict__ AF,
                                                      _Float16* __restrict__ ATF) {
    __shared__ _Float16 T64[64][TS];   // 9216 B
    const int tid = threadIdx.x;
    const int bi = blockIdx.x >> 6;
    const int bj = blockIdx.x & 63;
    const float4* adj4 = (const float4*)adj;

#pragma unroll
    for (int it = 0; it < 8; ++it) {
        const int vidx = it * 256 + tid;
        const int il = vidx >> 5, jq = vidx & 31;
        const float4 v = adj4[(size_t)(bi * 64 + il) * 2048 + bj * 32 + jq];
        union { _Float16 h[2]; unsigned u; } p;
        p.h[0] = (_Float16)(v.x + v.y);
        p.h[1] = (_Float16)(v.z + v.w);
        *(unsigned*)((char*)&T64[il][0] + jq * 4) = p.u;
    }
    __syncthreads();

    const int wave = tid >> 6, lane = tid & 63;
    const int r = lane & 15, g = lane >> 4;
#pragma unroll
    for (int c = 0; c < 2; ++c) {
        const half8 va = *(const half8*)((const char*)&T64[wave * 16 + r][0]
                                         + (c * 32 + g * 8) * 2);
        *(half8*)(AF + ((size_t)(bi * 4 + wave) * 128 + (bj * 2 + c)) * 512
                  + lane * 8) = va;
        half8 vt;
#pragma unroll
        for (int e = 0; e < 8; ++e) vt[e] = T64[c * 32 + g * 8 + e][wave * 16 + r];
        *(half8*)(ATF + ((size_t)(bj * 4 + wave) * 128 + (bi * 2 + c)) * 512
                  + lane * 8) = vt;
    }
}

// gemm (m97 pattern, round-7-verified). Block: 4 waves; owns output half,
// 4 M-tiles (wave w -> T0+w), 5 n-tiles (nh half), K-slice 2048 (64 S-steps,
// 16 chunks of 4). Chunk = 36 LDS units of 1 KB: u<16 A(T=u>>2, s=u&3),
// u>=16 B(nt=(u-16)>>2, s=(u-16)&3). Stage via global_load_lds width 16.
__global__ __launch_bounds__(256, 2) void gemm_kernel(const _Float16* __restrict__ AF,
                                                      const _Float16* __restrict__ ATF,
                                                      const _Float16* __restrict__ BF,
                                                      float* __restrict__ P) {
    __shared__ __align__(16) _Float16 lds[2][36 * 512];   // 73728 B
    const int tid = threadIdx.x;
    const int wave = tid >> 6, lane = tid & 63;
    const int r = lane & 15, g = lane >> 4;

    // bijective XCD swizzle (nwg=512, %8==0): contiguous 64-chunk per XCD
    const int o = (blockIdx.x & 7) * 64 + (blockIdx.x >> 3);
    const int ks = o & 1;              // K-split slice (of 2)
    const int nh = (o >> 1) & 1;       // n-half: nt 0..4 or 5..9
    const int Mblk = (o >> 2) & 63;
    const int isIn = (o >> 8) & 1;     // 0: h_out (AF), 1: h_in (ATF)

    const _Float16* Asrc = isIn ? ATF : AF;
    const int T0 = Mblk * 4;
    const int Sbase = ks * 64;

    f32x4 acc[5];
#pragma unroll
    for (int q = 0; q < 5; ++q) acc[q] = (f32x4){0.f, 0.f, 0.f, 0.f};

    // ---- stage chunk 0 ----
    {
        const int chunkS = Sbase;
#pragma unroll
        for (int k = 0; k < 9; ++k) {
            const int u = wave * 9 + k;
            const _Float16* src;
            if (u < 16) {
                src = Asrc + ((size_t)(T0 + (u >> 2)) * 128 + chunkS + (u & 3)) * 512;
            } else {
                const int v = u - 16;
                src = BF + ((size_t)(nh * 5 + (v >> 2)) * 128 + chunkS + (v & 3)) * 512;
            }
            __builtin_amdgcn_global_load_lds(
                (const __attribute__((address_space(1))) void*)(src + lane * 8),
                (__attribute__((address_space(3))) void*)(&lds[0][u * 512]),
                16, 0, 0);
        }
    }
    __syncthreads();

    for (int c = 0; c < 16; ++c) {
        const int buf = c & 1;
        if (c < 15) {   // issue next-chunk stage BEFORE compute
            const int chunkS = Sbase + (c + 1) * 4;
#pragma unroll
            for (int k = 0; k < 9; ++k) {
                const int u = wave * 9 + k;
                const _Float16* src;
                if (u < 16) {
                    src = Asrc + ((size_t)(T0 + (u >> 2)) * 128 + chunkS + (u & 3)) * 512;
                } else {
                    const int v = u - 16;
                    src = BF + ((size_t)(nh * 5 + (v >> 2)) * 128 + chunkS + (v & 3)) * 512;
                }
                __builtin_amdgcn_global_load_lds(
                    (const __attribute__((address_space(1))) void*)(src + lane * 8),
                    (__attribute__((address_space(3))) void*)(&lds[buf ^ 1][u * 512]),
                    16, 0, 0);
            }
        }
        // ---- compute chunk c from lds[buf] ----
        half8 a[4];
#pragma unroll
        for (int s = 0; s < 4; ++s)
            a[s] = *(const half8*)(&lds[buf][(wave * 4 + s) * 512 + lane * 8]);
#pragma unroll
        for (int q = 0; q < 5; ++q)
#pragma unroll
            for (int s = 0; s < 4; ++s) {
                const half8 b = *(const half8*)(&lds[buf][(16 + q * 4 + s) * 512
                                                          + lane * 8]);
                acc[q] = __builtin_amdgcn_mfma_f32_16x16x32_f16(a[s], b, acc[q], 0, 0, 0);
            }
        __syncthreads();   // drains this wave's gloads; releases buf for overwrite
    }

    // D layout: row = g*4+u, col = r (verified rounds 1-7)
    float* dst = P + (size_t)(isIn * 2 + ks) * LLDD;
    const int row = (T0 + wave) * 16 + g * 4;
#pragma unroll
    for (int q = 0; q < 5; ++q) {
        const int d = (nh * 5 + q) * 16 + r;
        if (d < DD) {
#pragma unroll
            for (int u = 0; u < 4; ++u)
                dst[(size_t)(row + u) * DD + d] = acc[q][u];
        }
    }
}

// out[0:LLDD) = h_in = P[2]+P[3]; out[LLDD:2*LLDD) = h_out = P[0]+P[1]
__global__ __launch_bounds__(256) void reduce_kernel(const float* __restrict__ P,
                                                     float* __restrict__ out) {
    const int idx = blockIdx.x * 256 + threadIdx.x;   // over 2*LLDD/4 float4s
    const int nv = LLDD / 4;
    const float4* p = (const float4*)P;
    const float4* src = (idx < nv) ? (p + (size_t)2 * nv) : p;   // h_in : h_out
    const int e = (idx < nv) ? idx : idx - nv;
    const float4 a = src[e], b = src[e + nv];
    float4 s;
    s.x = a.x + b.x;
    s.y = a.y + b.y;
    s.z = a.z + b.z;
    s.w = a.w + b.w;
    ((float4*)out)[idx] = s;
}

extern "C" void kernel_launch(void* const* d_in, const int* in_sizes, int n_in,
                              void* d_out, int out_size, void* d_ws, size_t ws_size,
                              hipStream_t stream) {
    const float* adj = (const float*)d_in[0];   // [4096, 4096, 2] fp32
    const float* h   = (const float*)d_in[1];   // [4096, 150] fp32
    float* out = (float*)d_out;
    _Float16* BF = (_Float16*)d_ws;                               // 1.31 MB
    float* P = (float*)((char*)d_ws + BF_BYTES);                  // 9.83 MB
    _Float16* AF = (_Float16*)((char*)d_ws + BF_BYTES + P_BYTES); // 33.55 MB
    _Float16* ATF = AF + (size_t)16777216;                        // 33.55 MB

    hipLaunchKernelGGL(prep_kernel, dim3(320), dim3(256), 0, stream, h, BF);
    hipLaunchKernelGGL(convert_kernel, dim3(4096), dim3(256), 0, stream, adj, AF, ATF);
    hipLaunchKernelGGL(gemm_kernel, dim3(512), dim3(256), 0, stream, AF, ATF, BF, P);
    hipLaunchKernelGGL(reduce_kernel, dim3(2 * LLDD / 4 / 256), dim3(256), 0, stream,
                       P, out);
}